// Round 1
// baseline (2608.756 us; speedup 1.0000x reference)
//
#include <hip/hip_runtime.h>
#include <math.h>
#include <float.h>

#define NN 20000
#define EE 320000
#define INDIM 16
#define HID 50
#define TW 5
#define FO 10
#define NGROUPS 64

// ---------- CSR build ----------
__global__ void k_deg(const int* __restrict__ dst, int* __restrict__ deg) {
    int e = blockIdx.x * 256 + threadIdx.x;
    if (e < EE) atomicAdd(&deg[dst[e]], 1);
}

__global__ void k_scan(const int* __restrict__ deg, int* __restrict__ offsets) {
    __shared__ int part[1024];
    const int CH = 20;  // 1024*20 >= NN
    int tid = threadIdx.x;
    int base = tid * CH;
    int loc[CH];
    int s = 0;
    for (int c = 0; c < CH; ++c) {
        int idx = base + c;
        int v = (idx < NN) ? deg[idx] : 0;
        loc[c] = s; s += v;
    }
    part[tid] = s; __syncthreads();
    for (int off = 1; off < 1024; off <<= 1) {
        int v = (tid >= off) ? part[tid - off] : 0;
        __syncthreads();
        part[tid] += v;
        __syncthreads();
    }
    int pre = (tid > 0) ? part[tid - 1] : 0;
    for (int c = 0; c < CH; ++c) {
        int idx = base + c;
        if (idx < NN) offsets[idx] = pre + loc[c];
    }
    if (tid == 0) offsets[NN] = part[1023];
}

__global__ void k_avglog(const int* __restrict__ deg, float* __restrict__ scal) {
    __shared__ float red[1024];
    int tid = threadIdx.x;
    float s = 0.f;
    for (int n = tid; n < NN; n += 1024) s += logf((float)deg[n] + 1.0f);
    red[tid] = s; __syncthreads();
    for (int off = 512; off > 0; off >>= 1) {
        if (tid < off) red[tid] += red[tid + off];
        __syncthreads();
    }
    if (tid == 0) scal[0] = red[0] / (float)NN;
}

__global__ void k_fill(const int* __restrict__ src, const int* __restrict__ dst,
                       const int* __restrict__ offsets, int* __restrict__ cursor,
                       int* __restrict__ csr_src) {
    int e = blockIdx.x * 256 + threadIdx.x;
    if (e < EE) {
        int d = dst[e];
        int pos = offsets[d] + atomicAdd(&cursor[d], 1);
        csr_src[pos] = src[e];
    }
}

// ---------- C = x@WL^T + b, P = x@WR^T  (pre_W is [T,F,2F] -> W2d[TF][2F]) ----------
template <int F, int TF>
__global__ void k_gemm_CP(const float* __restrict__ x, const float* __restrict__ W,
                          const float* __restrict__ b,
                          float* __restrict__ C, float* __restrict__ P) {
    const int NODES = 16;
    __shared__ float xs[NODES * F];
    int tid = threadIdx.x;
    int base = blockIdx.x * NODES;
    for (int idx = tid; idx < NODES * F; idx += 256) xs[idx] = x[(size_t)base * F + idx];
    __syncthreads();
    if (tid < TF) {
        float accC[NODES], accP[NODES];
#pragma unroll
        for (int n = 0; n < NODES; ++n) { accC[n] = 0.f; accP[n] = 0.f; }
        const float* Wr = W + (size_t)tid * 2 * F;
        for (int f = 0; f < F; ++f) {
            float wl = Wr[f], wr = Wr[F + f];
#pragma unroll
            for (int n = 0; n < NODES; ++n) {
                float xv = xs[n * F + f];
                accC[n] += xv * wl;
                accP[n] += xv * wr;
            }
        }
        float bb = b[tid];
        for (int n = 0; n < NODES; ++n) {
            C[((size_t)(base + n)) * TF + tid] = accC[n] + bb;
            P[((size_t)(base + n)) * TF + tid] = accP[n];
        }
    }
}

// ---------- fused aggregate + scalers + post-GEMM + lin, one block per node ----------
template <int F, int TF>
__global__ void k_agg_post(const float* __restrict__ C, const float* __restrict__ P,
                           const float* __restrict__ xin,
                           const int* __restrict__ offsets, const int* __restrict__ csr_src,
                           const float* __restrict__ scal,
                           const float* __restrict__ postW, const float* __restrict__ postb,
                           const float* __restrict__ linW, const float* __restrict__ linb,
                           float* __restrict__ hout) {
    __shared__ int s_src[256];
    __shared__ float s_agg[4][TF];
    __shared__ float s_x[F];
    __shared__ float s_y[HID];
    __shared__ float s_part[256];
    int tid = threadIdx.x;
    int i = blockIdx.x;
    int beg = offsets[i], end = offsets[i + 1];
    int d = end - beg;
    float S = 0.f, S2 = 0.f, mn = FLT_MAX, mx = -FLT_MAX;
    for (int j0 = beg; j0 < end; j0 += 256) {
        int nch = min(256, end - j0);
        if (tid < nch) s_src[tid] = csr_src[j0 + tid];
        __syncthreads();
        if (tid < TF) {
            for (int j = 0; j < nch; ++j) {
                float v = P[(size_t)s_src[j] * TF + tid];
                S += v; S2 += v * v;
                mn = fminf(mn, v); mx = fmaxf(mx, v);
            }
        }
        __syncthreads();
    }
    if (tid < TF) {
        float Cv = C[(size_t)i * TF + tid];
        float degf = (float)d;
        float degc = fmaxf(degf, 1.0f);
        float mean = (degf * Cv + S) / degc;
        float sumsq = degf * Cv * Cv + 2.0f * Cv * S + S2;
        float var = sumsq / degc - mean * mean;
        float stdv = sqrtf(fmaxf(var, 0.f) + 1e-5f);
        s_agg[0][tid] = mean;
        s_agg[1][tid] = (d > 0) ? Cv + mn : 0.f;
        s_agg[2][tid] = (d > 0) ? Cv + mx : 0.f;
        s_agg[3][tid] = stdv;
    }
    if (tid < F) s_x[tid] = xin[(size_t)i * F + tid];
    __syncthreads();
    // post-GEMM: y[k] = post_b[k] + post_W[k,:] . [x | agg | agg*amp | agg/amp]
    const int PT = 5;
    const int F13 = 13 * F;
    float degc = fmaxf((float)d, 1.0f);
    float amp = logf(degc + 1.0f) / scal[0];
    float inv_amp = 1.0f / amp;
    float acc = 0.f;
    if (tid < HID * PT) {
        int k = tid / PT, part = tid % PT;
        int t = k / FO;
        const int chunk = (F13 + PT - 1) / PT;
        int lo = part * chunk, hi = min(F13, lo + chunk);
        const float* Wrow = postW + (size_t)k * F13;
        for (int idx = lo; idx < hi; ++idx) {
            int blk = idx / F, f = idx % F;
            float feat;
            if (blk == 0)       feat = s_x[f];
            else if (blk < 5)   feat = s_agg[blk - 1][t * F + f];
            else if (blk < 9)   feat = s_agg[blk - 5][t * F + f] * amp;
            else                feat = s_agg[blk - 9][t * F + f] * inv_amp;
            acc += Wrow[idx] * feat;
        }
    }
    s_part[tid] = acc;
    __syncthreads();
    if (tid < HID) {
        float y = postb[tid];
#pragma unroll
        for (int p = 0; p < PT; ++p) y += s_part[tid * PT + p];
        s_y[tid] = y;
    }
    __syncthreads();
    if (tid < HID) {
        float o = linb[tid];
        const float* Wr = linW + (size_t)tid * HID;
        for (int k2 = 0; k2 < HID; ++k2) o += Wr[k2] * s_y[k2];
        hout[(size_t)i * HID + tid] = o;
    }
}

// ---------- BN (training-mode, biased var, exact two-pass) ----------
__global__ void k_bn_stats(const float* __restrict__ h, float* __restrict__ mu,
                           float* __restrict__ var) {
    __shared__ float red[256];
    int c = blockIdx.x, tid = threadIdx.x;
    float s = 0.f;
    for (int n = tid; n < NN; n += 256) s += h[(size_t)n * HID + c];
    red[tid] = s; __syncthreads();
    for (int off = 128; off > 0; off >>= 1) {
        if (tid < off) red[tid] += red[tid + off];
        __syncthreads();
    }
    float m = red[0] / (float)NN;
    __syncthreads();
    float s2 = 0.f;
    for (int n = tid; n < NN; n += 256) {
        float v = h[(size_t)n * HID + c] - m;
        s2 += v * v;
    }
    red[tid] = s2; __syncthreads();
    for (int off = 128; off > 0; off >>= 1) {
        if (tid < off) red[tid] += red[tid + off];
        __syncthreads();
    }
    if (tid == 0) { mu[c] = m; var[c] = red[0] / (float)NN; }
}

__global__ void k_bn_relu(const float* __restrict__ hin, const float* __restrict__ mu,
                          const float* __restrict__ var, const float* __restrict__ gamma,
                          const float* __restrict__ beta, float* __restrict__ hout) {
    int idx = blockIdx.x * 256 + threadIdx.x;
    if (idx < NN * HID) {
        int c = idx % HID;
        float v = hin[idx];
        float o = gamma[c] * (v - mu[c]) * rsqrtf(var[c] + 1e-5f) + beta[c];
        hout[idx] = fmaxf(o, 0.f);
    }
}

// ---------- pooling + head ----------
__global__ void k_gbounds(const int* __restrict__ batch, int* __restrict__ gstart) {
    int g = threadIdx.x;
    if (g <= NGROUPS) {
        int lo = 0, hi = NN;
        while (lo < hi) {
            int mid = (lo + hi) >> 1;
            if (batch[mid] < g) lo = mid + 1; else hi = mid;
        }
        gstart[g] = lo;
    }
}

__global__ void k_pool(const float* __restrict__ h, const int* __restrict__ gstart,
                       float* __restrict__ pooled) {
    int g = blockIdx.x, c = threadIdx.x;
    int beg = gstart[g], end = gstart[g + 1];
    if (c < HID) {
        float s = 0.f;
        for (int n = beg; n < end; ++n) s += h[(size_t)n * HID + c];
        pooled[g * HID + c] = s / fmaxf((float)(end - beg), 1.0f);
    }
}

__global__ void k_mlp(const float* __restrict__ pooled,
                      const float* __restrict__ W1, const float* __restrict__ b1,
                      const float* __restrict__ W2, const float* __restrict__ b2,
                      const float* __restrict__ W3, const float* __restrict__ b3,
                      float* __restrict__ out) {
    __shared__ float p[HID], h1[50], h2[25];
    int g = blockIdx.x, tid = threadIdx.x;
    if (tid < HID) p[tid] = pooled[g * HID + tid];
    __syncthreads();
    if (tid < 50) {
        float a = b1[tid];
        for (int k = 0; k < HID; ++k) a += W1[tid * HID + k] * p[k];
        h1[tid] = fmaxf(a, 0.f);
    }
    __syncthreads();
    if (tid < 25) {
        float a = b2[tid];
        for (int k = 0; k < 50; ++k) a += W2[tid * 50 + k] * h1[k];
        h2[tid] = fmaxf(a, 0.f);
    }
    __syncthreads();
    if (tid == 0) {
        float a = b3[0];
        for (int k = 0; k < 25; ++k) a += W3[k] * h2[k];
        out[g] = a;
    }
}

extern "C" void kernel_launch(void* const* d_in, const int* in_sizes, int n_in,
                              void* d_out, int out_size, void* d_ws, size_t ws_size,
                              hipStream_t stream) {
    const float* x      = (const float*)d_in[0];
    const int*   ei     = (const int*)d_in[1];
    const int*   batch  = (const int*)d_in[2];
    const float* preW0  = (const float*)d_in[3];
    const float* preb0  = (const float*)d_in[4];
    const float* postW0 = (const float*)d_in[5];
    const float* postb0 = (const float*)d_in[6];
    const float* linW0  = (const float*)d_in[7];
    const float* linb0  = (const float*)d_in[8];
    const float* gamma0 = (const float*)d_in[9];
    const float* beta0  = (const float*)d_in[10];
    const float* preW1  = (const float*)d_in[11];
    const float* preb1  = (const float*)d_in[12];
    const float* postW1 = (const float*)d_in[13];
    const float* postb1 = (const float*)d_in[14];
    const float* linW1  = (const float*)d_in[15];
    const float* linb1  = (const float*)d_in[16];
    const float* gamma1 = (const float*)d_in[17];
    const float* beta1  = (const float*)d_in[18];
    const float* mW1    = (const float*)d_in[19];
    const float* mb1    = (const float*)d_in[20];
    const float* mW2    = (const float*)d_in[21];
    const float* mb2    = (const float*)d_in[22];
    const float* mW3    = (const float*)d_in[23];
    const float* mb3    = (const float*)d_in[24];
    float* out = (float*)d_out;
    (void)in_sizes; (void)n_in; (void)out_size; (void)ws_size;

    char* ws = (char*)d_ws;
    size_t off = 0;
    auto alloc = [&](size_t bytes) -> void* {
        void* p = ws + off;
        off += (bytes + 255) & ~(size_t)255;
        return p;
    };
    int*   deg     = (int*)alloc((size_t)NN * 4);
    int*   offsets = (int*)alloc((size_t)(NN + 1) * 4);
    int*   cursor  = (int*)alloc((size_t)NN * 4);
    int*   csr_src = (int*)alloc((size_t)EE * 4);
    float* scal    = (float*)alloc(64);
    int*   gstart  = (int*)alloc((NGROUPS + 1) * 4);
    float* mu      = (float*)alloc(HID * 4);
    float* var     = (float*)alloc(HID * 4);
    float* pooled  = (float*)alloc(NGROUPS * HID * 4);
    float* Cbuf    = (float*)alloc((size_t)NN * 250 * 4);
    float* Pbuf    = (float*)alloc((size_t)NN * 250 * 4);
    float* h1buf   = (float*)alloc((size_t)NN * HID * 4);
    float* h2buf   = (float*)alloc((size_t)NN * HID * 4);

    const int* src = ei;
    const int* dst = ei + EE;

    hipMemsetAsync(deg, 0, (size_t)NN * 4, stream);
    hipMemsetAsync(cursor, 0, (size_t)NN * 4, stream);
    k_deg<<<EE / 256, 256, 0, stream>>>(dst, deg);
    k_scan<<<1, 1024, 0, stream>>>(deg, offsets);
    k_avglog<<<1, 1024, 0, stream>>>(deg, scal);
    k_fill<<<EE / 256, 256, 0, stream>>>(src, dst, offsets, cursor, csr_src);

    // ---- conv0 (F=16, TF=80) ----
    k_gemm_CP<INDIM, TW * INDIM><<<NN / 16, 256, 0, stream>>>(x, preW0, preb0, Cbuf, Pbuf);
    k_agg_post<INDIM, TW * INDIM><<<NN, 256, 0, stream>>>(Cbuf, Pbuf, x, offsets, csr_src,
                                                          scal, postW0, postb0, linW0, linb0, h1buf);
    k_bn_stats<<<HID, 256, 0, stream>>>(h1buf, mu, var);
    k_bn_relu<<<(NN * HID + 255) / 256, 256, 0, stream>>>(h1buf, mu, var, gamma0, beta0, h1buf);

    // ---- conv1 (F=50, TF=250) ----
    k_gemm_CP<HID, TW * HID><<<NN / 16, 256, 0, stream>>>(h1buf, preW1, preb1, Cbuf, Pbuf);
    k_agg_post<HID, TW * HID><<<NN, 256, 0, stream>>>(Cbuf, Pbuf, h1buf, offsets, csr_src,
                                                      scal, postW1, postb1, linW1, linb1, h2buf);
    k_bn_stats<<<HID, 256, 0, stream>>>(h2buf, mu, var);
    k_bn_relu<<<(NN * HID + 255) / 256, 256, 0, stream>>>(h2buf, mu, var, gamma1, beta1, h2buf);

    // ---- pool + head ----
    k_gbounds<<<1, 128, 0, stream>>>(batch, gstart);
    k_pool<<<NGROUPS, 64, 0, stream>>>(h2buf, gstart, pooled);
    k_mlp<<<NGROUPS, 64, 0, stream>>>(pooled, mW1, mb1, mW2, mb2, mW3, mb3, out);
}

// Round 2
// 677.405 us; speedup vs baseline: 3.8511x; 3.8511x over previous
//
#include <hip/hip_runtime.h>
#include <math.h>
#include <float.h>

#define NN 20000
#define EE 320000
#define INDIM 16
#define HID 50
#define TW 5
#define FO 10
#define NGROUPS 64

typedef float f4 __attribute__((ext_vector_type(4)));

__device__ inline f4 f4_min(f4 a, f4 b) {
    f4 r; r.x = fminf(a.x, b.x); r.y = fminf(a.y, b.y);
    r.z = fminf(a.z, b.z); r.w = fminf(a.w, b.w); return r;
}
__device__ inline f4 f4_max(f4 a, f4 b) {
    f4 r; r.x = fmaxf(a.x, b.x); r.y = fmaxf(a.y, b.y);
    r.z = fmaxf(a.z, b.z); r.w = fmaxf(a.w, b.w); return r;
}

// ---------- CSR build ----------
__global__ void k_deg(const int* __restrict__ dst, int* __restrict__ deg) {
    int e = blockIdx.x * 256 + threadIdx.x;
    if (e < EE) atomicAdd(&deg[dst[e]], 1);
}

__global__ void k_scan(const int* __restrict__ deg, int* __restrict__ offsets) {
    __shared__ int part[1024];
    const int CH = 20;  // 1024*20 >= NN
    int tid = threadIdx.x;
    int base = tid * CH;
    int loc[CH];
    int s = 0;
    for (int c = 0; c < CH; ++c) {
        int idx = base + c;
        int v = (idx < NN) ? deg[idx] : 0;
        loc[c] = s; s += v;
    }
    part[tid] = s; __syncthreads();
    for (int off = 1; off < 1024; off <<= 1) {
        int v = (tid >= off) ? part[tid - off] : 0;
        __syncthreads();
        part[tid] += v;
        __syncthreads();
    }
    int pre = (tid > 0) ? part[tid - 1] : 0;
    for (int c = 0; c < CH; ++c) {
        int idx = base + c;
        if (idx < NN) offsets[idx] = pre + loc[c];
    }
    if (tid == 0) offsets[NN] = part[1023];
}

__global__ void k_avglog(const int* __restrict__ deg, float* __restrict__ scal) {
    __shared__ float red[1024];
    int tid = threadIdx.x;
    float s = 0.f;
    for (int n = tid; n < NN; n += 1024) s += logf((float)deg[n] + 1.0f);
    red[tid] = s; __syncthreads();
    for (int off = 512; off > 0; off >>= 1) {
        if (tid < off) red[tid] += red[tid + off];
        __syncthreads();
    }
    if (tid == 0) scal[0] = red[0] / (float)NN;
}

__global__ void k_fill(const int* __restrict__ src, const int* __restrict__ dst,
                       const int* __restrict__ offsets, int* __restrict__ cursor,
                       int* __restrict__ csr_src) {
    int e = blockIdx.x * 256 + threadIdx.x;
    if (e < EE) {
        int d = dst[e];
        int pos = offsets[d] + atomicAdd(&cursor[d], 1);
        csr_src[pos] = src[e];
    }
}

// ---------- C = x@WL^T + b, P = x@WR^T  (pre_W is [T,F,2F]), padded stride TFP ----------
template <int F, int TF, int TFP>
__global__ void k_gemm_CP(const float* __restrict__ x, const float* __restrict__ W,
                          const float* __restrict__ b,
                          float* __restrict__ C, float* __restrict__ P) {
    const int NODES = 16;
    __shared__ float xs[NODES * F];
    int tid = threadIdx.x;
    int base = blockIdx.x * NODES;
    for (int idx = tid; idx < NODES * F; idx += 256) xs[idx] = x[(size_t)base * F + idx];
    __syncthreads();
    if (tid < TF) {
        float accC[NODES], accP[NODES];
#pragma unroll
        for (int n = 0; n < NODES; ++n) { accC[n] = 0.f; accP[n] = 0.f; }
        const float* Wr = W + (size_t)tid * 2 * F;
        for (int f = 0; f < F; ++f) {
            float wl = Wr[f], wr = Wr[F + f];
#pragma unroll
            for (int n = 0; n < NODES; ++n) {
                float xv = xs[n * F + f];
                accC[n] += xv * wl;
                accP[n] += xv * wr;
            }
        }
        float bb = b[tid];
        for (int n = 0; n < NODES; ++n) {
            C[((size_t)(base + n)) * TFP + tid] = accC[n] + bb;
            P[((size_t)(base + n)) * TFP + tid] = accP[n];
        }
    }
}

// ---------- fused gather-stats + scalers + post-GEMM + lin ----------
// 4 nodes per block, one wave per node. Gather: lane g owns f4 channel group g.
template <int F, int TF, int TFP>
__global__ __launch_bounds__(256) void k_conv(
    const float* __restrict__ xin, const float* __restrict__ C, const float* __restrict__ P,
    const int* __restrict__ offsets, const int* __restrict__ csr,
    const float* __restrict__ scal,
    const float* __restrict__ postW, const float* __restrict__ postb,
    const float* __restrict__ linW, const float* __restrict__ linb,
    float* __restrict__ hout) {
    const int NB = 4;
    const int G = TFP / 4;
    __shared__ __align__(16) float sA[NB][4][TFP];
    __shared__ float sx[NB][F];
    __shared__ float sy[NB][HID];
    __shared__ float samp[NB][2];
    int t = threadIdx.x;
    int nsub = t >> 6, lane = t & 63;
    int i = blockIdx.x * NB + nsub;
    int beg = offsets[i], end = offsets[i + 1];
    int d = end - beg;

    if (lane < G) {
        const f4* __restrict__ Pv = (const f4*)P;
        f4 Sa = {0.f, 0.f, 0.f, 0.f}, S2a = {0.f, 0.f, 0.f, 0.f};
        f4 Sb = {0.f, 0.f, 0.f, 0.f}, S2b = {0.f, 0.f, 0.f, 0.f};
        f4 MNa = {FLT_MAX, FLT_MAX, FLT_MAX, FLT_MAX};
        f4 MXa = {-FLT_MAX, -FLT_MAX, -FLT_MAX, -FLT_MAX};
        f4 MNb = MNa, MXb = MXa;
        int j = beg;
        for (; j + 4 <= end; j += 4) {
            int s0 = csr[j], s1 = csr[j + 1], s2 = csr[j + 2], s3 = csr[j + 3];
            f4 a = Pv[(size_t)s0 * G + lane];
            f4 b = Pv[(size_t)s1 * G + lane];
            f4 c = Pv[(size_t)s2 * G + lane];
            f4 e = Pv[(size_t)s3 * G + lane];
            Sa += a; S2a += a * a; MNa = f4_min(MNa, a); MXa = f4_max(MXa, a);
            Sb += b; S2b += b * b; MNb = f4_min(MNb, b); MXb = f4_max(MXb, b);
            Sa += c; S2a += c * c; MNa = f4_min(MNa, c); MXa = f4_max(MXa, c);
            Sb += e; S2b += e * e; MNb = f4_min(MNb, e); MXb = f4_max(MXb, e);
        }
        for (; j < end; ++j) {
            int s0 = csr[j];
            f4 a = Pv[(size_t)s0 * G + lane];
            Sa += a; S2a += a * a; MNa = f4_min(MNa, a); MXa = f4_max(MXa, a);
        }
        f4 S = Sa + Sb, S2 = S2a + S2b;
        f4 MN = f4_min(MNa, MNb), MX = f4_max(MXa, MXb);
        f4 Cv = ((const f4*)C)[(size_t)i * G + lane];
        float degf = (float)d;
        float rdegc = 1.0f / fmaxf(degf, 1.0f);
        f4 mean, sq, var, stdv, mnv, mxv;
        mean.x = (degf * Cv.x + S.x) * rdegc; mean.y = (degf * Cv.y + S.y) * rdegc;
        mean.z = (degf * Cv.z + S.z) * rdegc; mean.w = (degf * Cv.w + S.w) * rdegc;
        sq.x = degf * Cv.x * Cv.x + 2.f * Cv.x * S.x + S2.x;
        sq.y = degf * Cv.y * Cv.y + 2.f * Cv.y * S.y + S2.y;
        sq.z = degf * Cv.z * Cv.z + 2.f * Cv.z * S.z + S2.z;
        sq.w = degf * Cv.w * Cv.w + 2.f * Cv.w * S.w + S2.w;
        var.x = sq.x * rdegc - mean.x * mean.x; var.y = sq.y * rdegc - mean.y * mean.y;
        var.z = sq.z * rdegc - mean.z * mean.z; var.w = sq.w * rdegc - mean.w * mean.w;
        stdv.x = sqrtf(fmaxf(var.x, 0.f) + 1e-5f); stdv.y = sqrtf(fmaxf(var.y, 0.f) + 1e-5f);
        stdv.z = sqrtf(fmaxf(var.z, 0.f) + 1e-5f); stdv.w = sqrtf(fmaxf(var.w, 0.f) + 1e-5f);
        if (d > 0) {
            mnv.x = Cv.x + MN.x; mnv.y = Cv.y + MN.y; mnv.z = Cv.z + MN.z; mnv.w = Cv.w + MN.w;
            mxv.x = Cv.x + MX.x; mxv.y = Cv.y + MX.y; mxv.z = Cv.z + MX.z; mxv.w = Cv.w + MX.w;
        } else {
            mnv = (f4){0.f, 0.f, 0.f, 0.f}; mxv = mnv;
        }
        ((f4*)&sA[nsub][0][0])[lane] = mean;
        ((f4*)&sA[nsub][1][0])[lane] = mnv;
        ((f4*)&sA[nsub][2][0])[lane] = mxv;
        ((f4*)&sA[nsub][3][0])[lane] = stdv;
    }
    if (lane < F) sx[nsub][lane] = xin[(size_t)i * F + lane];
    if (lane == 0) {
        float amp = logf(fmaxf((float)d, 1.f) + 1.f) / scal[0];
        samp[nsub][0] = amp; samp[nsub][1] = 1.f / amp;
    }
    __syncthreads();

    int k = lane;
    if (k < HID) {
        int tw = k / FO;
        const float* __restrict__ Wr = postW + (size_t)k * (13 * F);
        float amp = samp[nsub][0], ia = samp[nsub][1];
        float y = postb[k];
        for (int f = 0; f < F; ++f) y += Wr[f] * sx[nsub][f];
        int idx = F;
        for (int s = 0; s < 4; ++s) {
            const float* A = &sA[nsub][s][tw * F];
            for (int f = 0; f < F; ++f) y += Wr[idx++] * A[f];
        }
        for (int s = 0; s < 4; ++s) {
            const float* A = &sA[nsub][s][tw * F];
            for (int f = 0; f < F; ++f) y += Wr[idx++] * (A[f] * amp);
        }
        for (int s = 0; s < 4; ++s) {
            const float* A = &sA[nsub][s][tw * F];
            for (int f = 0; f < F; ++f) y += Wr[idx++] * (A[f] * ia);
        }
        sy[nsub][k] = y;
    }
    __syncthreads();
    if (k < HID) {
        float o = linb[k];
        const float* __restrict__ L = linW + (size_t)k * HID;
        for (int j2 = 0; j2 < HID; ++j2) o += L[j2] * sy[nsub][j2];
        hout[(size_t)i * HID + k] = o;
    }
}

// ---------- BN: one-pass partial sums (coalesced) + apply ----------
__global__ void k_bn_part(const float* __restrict__ h, float* __restrict__ acc) {
    __shared__ float ss[4][64], ss2[4][64];
    int t = threadIdx.x;
    int rs = t >> 6, c = t & 63;
    float s = 0.f, s2 = 0.f;
    if (c < HID) {
        int r0 = blockIdx.x * 200 + rs;
        int rend = blockIdx.x * 200 + 200;
        if (rend > NN) rend = NN;
        for (int r = r0; r < rend; r += 4) {
            float v = h[(size_t)r * HID + c];
            s += v; s2 += v * v;
        }
    }
    ss[rs][c] = s; ss2[rs][c] = s2;
    __syncthreads();
    if (t < HID) {
        float S = ss[0][t] + ss[1][t] + ss[2][t] + ss[3][t];
        float S2 = ss2[0][t] + ss2[1][t] + ss2[2][t] + ss2[3][t];
        atomicAdd(&acc[t], S);
        atomicAdd(&acc[64 + t], S2);
    }
}

__global__ void k_bn_relu(const float* __restrict__ hin, const float* __restrict__ acc,
                          const float* __restrict__ gamma, const float* __restrict__ beta,
                          float* __restrict__ hout) {
    int idx = blockIdx.x * 256 + threadIdx.x;
    if (idx < NN * HID) {
        int c = idx % HID;
        float mu = acc[c] * (1.f / NN);
        float var = acc[64 + c] * (1.f / NN) - mu * mu;
        float v = hin[idx];
        hout[idx] = fmaxf(gamma[c] * (v - mu) * rsqrtf(var + 1e-5f) + beta[c], 0.f);
    }
}

// ---------- pooling + head ----------
__global__ void k_gbounds(const int* __restrict__ batch, int* __restrict__ gstart) {
    int g = threadIdx.x;
    if (g <= NGROUPS) {
        int lo = 0, hi = NN;
        while (lo < hi) {
            int mid = (lo + hi) >> 1;
            if (batch[mid] < g) lo = mid + 1; else hi = mid;
        }
        gstart[g] = lo;
    }
}

__global__ void k_pool(const float* __restrict__ h, const int* __restrict__ gstart,
                       float* __restrict__ pooled) {
    int g = blockIdx.x, c = threadIdx.x;
    int beg = gstart[g], end = gstart[g + 1];
    if (c < HID) {
        float s = 0.f;
        for (int n = beg; n < end; ++n) s += h[(size_t)n * HID + c];
        pooled[g * HID + c] = s / fmaxf((float)(end - beg), 1.0f);
    }
}

__global__ void k_mlp(const float* __restrict__ pooled,
                      const float* __restrict__ W1, const float* __restrict__ b1,
                      const float* __restrict__ W2, const float* __restrict__ b2,
                      const float* __restrict__ W3, const float* __restrict__ b3,
                      float* __restrict__ out) {
    __shared__ float p[HID], h1[50], h2[25];
    int g = blockIdx.x, tid = threadIdx.x;
    if (tid < HID) p[tid] = pooled[g * HID + tid];
    __syncthreads();
    if (tid < 50) {
        float a = b1[tid];
        for (int k = 0; k < HID; ++k) a += W1[tid * HID + k] * p[k];
        h1[tid] = fmaxf(a, 0.f);
    }
    __syncthreads();
    if (tid < 25) {
        float a = b2[tid];
        for (int k = 0; k < 50; ++k) a += W2[tid * 50 + k] * h1[k];
        h2[tid] = fmaxf(a, 0.f);
    }
    __syncthreads();
    if (tid == 0) {
        float a = b3[0];
        for (int k = 0; k < 25; ++k) a += W3[k] * h2[k];
        out[g] = a;
    }
}

extern "C" void kernel_launch(void* const* d_in, const int* in_sizes, int n_in,
                              void* d_out, int out_size, void* d_ws, size_t ws_size,
                              hipStream_t stream) {
    const float* x      = (const float*)d_in[0];
    const int*   ei     = (const int*)d_in[1];
    const int*   batch  = (const int*)d_in[2];
    const float* preW0  = (const float*)d_in[3];
    const float* preb0  = (const float*)d_in[4];
    const float* postW0 = (const float*)d_in[5];
    const float* postb0 = (const float*)d_in[6];
    const float* linW0  = (const float*)d_in[7];
    const float* linb0  = (const float*)d_in[8];
    const float* gamma0 = (const float*)d_in[9];
    const float* beta0  = (const float*)d_in[10];
    const float* preW1  = (const float*)d_in[11];
    const float* preb1  = (const float*)d_in[12];
    const float* postW1 = (const float*)d_in[13];
    const float* postb1 = (const float*)d_in[14];
    const float* linW1  = (const float*)d_in[15];
    const float* linb1  = (const float*)d_in[16];
    const float* gamma1 = (const float*)d_in[17];
    const float* beta1  = (const float*)d_in[18];
    const float* mW1    = (const float*)d_in[19];
    const float* mb1    = (const float*)d_in[20];
    const float* mW2    = (const float*)d_in[21];
    const float* mb2    = (const float*)d_in[22];
    const float* mW3    = (const float*)d_in[23];
    const float* mb3    = (const float*)d_in[24];
    float* out = (float*)d_out;
    (void)in_sizes; (void)n_in; (void)out_size; (void)ws_size;

    char* ws = (char*)d_ws;
    size_t off = 0;
    auto alloc = [&](size_t bytes) -> void* {
        void* p = ws + off;
        off += (bytes + 255) & ~(size_t)255;
        return p;
    };
    int*   deg     = (int*)alloc((size_t)NN * 4);
    int*   offsets = (int*)alloc((size_t)(NN + 1) * 4);
    int*   cursor  = (int*)alloc((size_t)NN * 4);
    int*   csr_src = (int*)alloc((size_t)EE * 4);
    float* scal    = (float*)alloc(64);
    int*   gstart  = (int*)alloc((NGROUPS + 1) * 4);
    float* bnacc0  = (float*)alloc(128 * 4);
    float* bnacc1  = (float*)alloc(128 * 4);
    float* pooled  = (float*)alloc(NGROUPS * HID * 4);
    float* Cbuf    = (float*)alloc((size_t)NN * 256 * 4);
    float* Pbuf    = (float*)alloc((size_t)NN * 256 * 4);
    float* h1buf   = (float*)alloc((size_t)NN * HID * 4);
    float* h2buf   = (float*)alloc((size_t)NN * HID * 4);

    const int* src = ei;
    const int* dst = ei + EE;

    hipMemsetAsync(deg, 0, (size_t)NN * 4, stream);
    hipMemsetAsync(cursor, 0, (size_t)NN * 4, stream);
    hipMemsetAsync(bnacc0, 0, 128 * 4, stream);
    hipMemsetAsync(bnacc1, 0, 128 * 4, stream);
    k_deg<<<EE / 256, 256, 0, stream>>>(dst, deg);
    k_scan<<<1, 1024, 0, stream>>>(deg, offsets);
    k_avglog<<<1, 1024, 0, stream>>>(deg, scal);
    k_fill<<<EE / 256, 256, 0, stream>>>(src, dst, offsets, cursor, csr_src);

    // ---- conv0 (F=16, TF=80, TFP=80) ----
    k_gemm_CP<INDIM, TW * INDIM, 80><<<NN / 16, 256, 0, stream>>>(x, preW0, preb0, Cbuf, Pbuf);
    k_conv<INDIM, TW * INDIM, 80><<<NN / 4, 256, 0, stream>>>(x, Cbuf, Pbuf, offsets, csr_src,
                                                              scal, postW0, postb0, linW0, linb0, h1buf);
    k_bn_part<<<100, 256, 0, stream>>>(h1buf, bnacc0);
    k_bn_relu<<<(NN * HID + 255) / 256, 256, 0, stream>>>(h1buf, bnacc0, gamma0, beta0, h1buf);

    // ---- conv1 (F=50, TF=250, TFP=256) ----
    k_gemm_CP<HID, TW * HID, 256><<<NN / 16, 256, 0, stream>>>(h1buf, preW1, preb1, Cbuf, Pbuf);
    k_conv<HID, TW * HID, 256><<<NN / 4, 256, 0, stream>>>(h1buf, Cbuf, Pbuf, offsets, csr_src,
                                                           scal, postW1, postb1, linW1, linb1, h2buf);
    k_bn_part<<<100, 256, 0, stream>>>(h2buf, bnacc1);
    k_bn_relu<<<(NN * HID + 255) / 256, 256, 0, stream>>>(h2buf, bnacc1, gamma1, beta1, h2buf);

    // ---- pool + head ----
    k_gbounds<<<1, 128, 0, stream>>>(batch, gstart);
    k_pool<<<NGROUPS, 64, 0, stream>>>(h2buf, gstart, pooled);
    k_mlp<<<NGROUPS, 64, 0, stream>>>(pooled, mW1, mb1, mW2, mb2, mW3, mb3, out);
}

// Round 3
// 468.347 us; speedup vs baseline: 5.5701x; 1.4464x over previous
//
#include <hip/hip_runtime.h>
#include <math.h>
#include <float.h>

#define NN 20000
#define EE 320000
#define INDIM 16
#define HID 50
#define TW 5
#define FO 10
#define NGROUPS 64

typedef float f4 __attribute__((ext_vector_type(4)));

__device__ inline f4 f4_min(f4 a, f4 b) {
    f4 r; r.x = fminf(a.x, b.x); r.y = fminf(a.y, b.y);
    r.z = fminf(a.z, b.z); r.w = fminf(a.w, b.w); return r;
}
__device__ inline f4 f4_max(f4 a, f4 b) {
    f4 r; r.x = fmaxf(a.x, b.x); r.y = fmaxf(a.y, b.y);
    r.z = fmaxf(a.z, b.z); r.w = fmaxf(a.w, b.w); return r;
}
__device__ inline float sh3sum(float v, int g0, int G_) {
    return v + __shfl(v, g0 + G_, 64) + __shfl(v, g0 + 2 * G_, 64);
}
__device__ inline float sh3min(float v, int g0, int G_) {
    return fminf(fminf(v, __shfl(v, g0 + G_, 64)), __shfl(v, g0 + 2 * G_, 64));
}
__device__ inline float sh3max(float v, int g0, int G_) {
    return fmaxf(fmaxf(v, __shfl(v, g0 + G_, 64)), __shfl(v, g0 + 2 * G_, 64));
}

// ---------- CSR build ----------
__global__ void k_deg(const int* __restrict__ dst, int* __restrict__ deg) {
    int e = blockIdx.x * 256 + threadIdx.x;
    if (e < EE) atomicAdd(&deg[dst[e]], 1);
}

__global__ void k_scan(const int* __restrict__ deg, int* __restrict__ offsets) {
    __shared__ int part[1024];
    const int CH = 20;
    int tid = threadIdx.x;
    int base = tid * CH;
    int loc[CH];
    int s = 0;
    for (int c = 0; c < CH; ++c) {
        int idx = base + c;
        int v = (idx < NN) ? deg[idx] : 0;
        loc[c] = s; s += v;
    }
    part[tid] = s; __syncthreads();
    for (int off = 1; off < 1024; off <<= 1) {
        int v = (tid >= off) ? part[tid - off] : 0;
        __syncthreads();
        part[tid] += v;
        __syncthreads();
    }
    int pre = (tid > 0) ? part[tid - 1] : 0;
    for (int c = 0; c < CH; ++c) {
        int idx = base + c;
        if (idx < NN) offsets[idx] = pre + loc[c];
    }
    if (tid == 0) offsets[NN] = part[1023];
}

__global__ void k_avglog(const int* __restrict__ deg, float* __restrict__ scal) {
    __shared__ float red[1024];
    int tid = threadIdx.x;
    float s = 0.f;
    for (int n = tid; n < NN; n += 1024) s += logf((float)deg[n] + 1.0f);
    red[tid] = s; __syncthreads();
    for (int off = 512; off > 0; off >>= 1) {
        if (tid < off) red[tid] += red[tid + off];
        __syncthreads();
    }
    if (tid == 0) scal[0] = red[0] / (float)NN;
}

__global__ void k_fill(const int* __restrict__ src, const int* __restrict__ dst,
                       const int* __restrict__ offsets, int* __restrict__ cursor,
                       int* __restrict__ csr_src) {
    int e = blockIdx.x * 256 + threadIdx.x;
    if (e < EE) {
        int d = dst[e];
        int pos = offsets[d] + atomicAdd(&cursor[d], 1);
        csr_src[pos] = src[e];
    }
}

// ---------- generic transpose: dst[C][DP], dst[c*DP+r] = (r<R)? src[r*C+c] : 0 ----------
__global__ void k_transpose(const float* __restrict__ src, float* __restrict__ dst,
                            int R, int C, int DP) {
    int idx = blockIdx.x * 256 + threadIdx.x;
    if (idx < C * DP) {
        int c = idx / DP, r = idx - c * DP;
        dst[idx] = (r < R) ? src[r * C + c] : 0.f;
    }
}

// ---------- C = x@WL^T + b, P = x@WR^T with transposed weights preWt[2F][TFP] ----------
template <int F, int TF, int TFP>
__global__ __launch_bounds__(256, 4) void k_gemm_CP(
    const float* __restrict__ x, const float* __restrict__ preWt,
    const float* __restrict__ b,
    float* __restrict__ C, float* __restrict__ P) {
    const int NODES = 16;
    __shared__ float xs[NODES * F];
    int tid = threadIdx.x;
    int base = blockIdx.x * NODES;
    for (int idx = tid; idx < NODES * F; idx += 256) xs[idx] = x[(size_t)base * F + idx];
    __syncthreads();
    if (tid < TF) {
        float accC[NODES], accP[NODES];
#pragma unroll
        for (int n = 0; n < NODES; ++n) { accC[n] = 0.f; accP[n] = 0.f; }
        for (int f = 0; f < F; ++f) {
            float wl = preWt[f * TFP + tid];
            float wr = preWt[(F + f) * TFP + tid];
#pragma unroll
            for (int n = 0; n < NODES; ++n) {
                float xv = xs[n * F + f];
                accC[n] += xv * wl;
                accP[n] += xv * wr;
            }
        }
        float bb = b[tid];
        for (int n = 0; n < NODES; ++n) {
            C[((size_t)(base + n)) * TFP + tid] = accC[n] + bb;
            P[((size_t)(base + n)) * TFP + tid] = accP[n];
        }
    } else if (tid < TFP) {
        for (int n = 0; n < NODES; ++n) {
            C[((size_t)(base + n)) * TFP + tid] = 0.f;
            P[((size_t)(base + n)) * TFP + tid] = 0.f;
        }
    }
}

// ---------- fused gather-stats + post-GEMM + lin ----------
// 4 nodes/block, one wave per node. EP = edges processed in parallel lane-groups.
template <int F, int TF, int TFP, int EP>
__global__ __launch_bounds__(256, 4) void k_conv(
    const float* __restrict__ xin, const float* __restrict__ C, const float* __restrict__ P,
    const int* __restrict__ offsets, const int* __restrict__ csr,
    const float* __restrict__ scal,
    const float* __restrict__ Wt,   // [13F][64] transposed post weights
    const float* __restrict__ postb,
    const float* __restrict__ Lt,   // [HID][64] transposed lin weights
    const float* __restrict__ linb,
    float* __restrict__ hout) {
    const int NB = 4;
    const int G = TFP / 4;
    __shared__ __align__(16) float sAgg[NB][4][TFP];
    __shared__ float sX[NB][F];
    __shared__ float sY[NB][HID];
    __shared__ float samp[NB][2];
    int t = threadIdx.x;
    int nsub = t >> 6, lane = t & 63;
    int i = blockIdx.x * NB + nsub;
    int beg = offsets[i], end = offsets[i + 1];
    int d = end - beg;

    int g = (EP == 1) ? lane : (lane % G);
    int e = (EP == 1) ? 0 : (lane / G);
    bool act = (EP == 1) ? (g < G) : (e < EP);

    f4 S = {0.f, 0.f, 0.f, 0.f}, S2 = {0.f, 0.f, 0.f, 0.f};
    f4 MN = {FLT_MAX, FLT_MAX, FLT_MAX, FLT_MAX};
    f4 MX = {-FLT_MAX, -FLT_MAX, -FLT_MAX, -FLT_MAX};
    const f4* __restrict__ Pv = (const f4*)P;

    if (act) {
        if (EP == 1) {
            int j = beg;
            for (; j + 4 <= end; j += 4) {
                int s0 = csr[j], s1 = csr[j + 1], s2 = csr[j + 2], s3 = csr[j + 3];
                f4 a = Pv[(size_t)s0 * G + g];
                f4 b = Pv[(size_t)s1 * G + g];
                f4 c = Pv[(size_t)s2 * G + g];
                f4 dd = Pv[(size_t)s3 * G + g];
                S += a; S2 += a * a; MN = f4_min(MN, a); MX = f4_max(MX, a);
                S += b; S2 += b * b; MN = f4_min(MN, b); MX = f4_max(MX, b);
                S += c; S2 += c * c; MN = f4_min(MN, c); MX = f4_max(MX, c);
                S += dd; S2 += dd * dd; MN = f4_min(MN, dd); MX = f4_max(MX, dd);
            }
            for (; j < end; ++j) {
                int s0 = csr[j];
                f4 a = Pv[(size_t)s0 * G + g];
                S += a; S2 += a * a; MN = f4_min(MN, a); MX = f4_max(MX, a);
            }
        } else {
            int j = beg + e;
            for (; j + EP < end; j += 2 * EP) {
                int s0 = csr[j], s1 = csr[j + EP];
                f4 a = Pv[(size_t)s0 * G + g];
                f4 b = Pv[(size_t)s1 * G + g];
                S += a; S2 += a * a; MN = f4_min(MN, a); MX = f4_max(MX, a);
                S += b; S2 += b * b; MN = f4_min(MN, b); MX = f4_max(MX, b);
            }
            if (j < end) {
                int s0 = csr[j];
                f4 a = Pv[(size_t)s0 * G + g];
                S += a; S2 += a * a; MN = f4_min(MN, a); MX = f4_max(MX, a);
            }
        }
    }
    if (EP == 3) {
        int g0 = lane % G;
        S.x = sh3sum(S.x, g0, G); S.y = sh3sum(S.y, g0, G);
        S.z = sh3sum(S.z, g0, G); S.w = sh3sum(S.w, g0, G);
        S2.x = sh3sum(S2.x, g0, G); S2.y = sh3sum(S2.y, g0, G);
        S2.z = sh3sum(S2.z, g0, G); S2.w = sh3sum(S2.w, g0, G);
        MN.x = sh3min(MN.x, g0, G); MN.y = sh3min(MN.y, g0, G);
        MN.z = sh3min(MN.z, g0, G); MN.w = sh3min(MN.w, g0, G);
        MX.x = sh3max(MX.x, g0, G); MX.y = sh3max(MX.y, g0, G);
        MX.z = sh3max(MX.z, g0, G); MX.w = sh3max(MX.w, g0, G);
    }

    if (lane < G) {
        f4 Cv = ((const f4*)C)[(size_t)i * G + lane];
        float degf = (float)d;
        float rdegc = 1.0f / fmaxf(degf, 1.0f);
        f4 mean, sq, var, stdv, mnv, mxv;
        mean.x = (degf * Cv.x + S.x) * rdegc; mean.y = (degf * Cv.y + S.y) * rdegc;
        mean.z = (degf * Cv.z + S.z) * rdegc; mean.w = (degf * Cv.w + S.w) * rdegc;
        sq.x = degf * Cv.x * Cv.x + 2.f * Cv.x * S.x + S2.x;
        sq.y = degf * Cv.y * Cv.y + 2.f * Cv.y * S.y + S2.y;
        sq.z = degf * Cv.z * Cv.z + 2.f * Cv.z * S.z + S2.z;
        sq.w = degf * Cv.w * Cv.w + 2.f * Cv.w * S.w + S2.w;
        var.x = sq.x * rdegc - mean.x * mean.x; var.y = sq.y * rdegc - mean.y * mean.y;
        var.z = sq.z * rdegc - mean.z * mean.z; var.w = sq.w * rdegc - mean.w * mean.w;
        stdv.x = sqrtf(fmaxf(var.x, 0.f) + 1e-5f); stdv.y = sqrtf(fmaxf(var.y, 0.f) + 1e-5f);
        stdv.z = sqrtf(fmaxf(var.z, 0.f) + 1e-5f); stdv.w = sqrtf(fmaxf(var.w, 0.f) + 1e-5f);
        if (d > 0) {
            mnv.x = Cv.x + MN.x; mnv.y = Cv.y + MN.y; mnv.z = Cv.z + MN.z; mnv.w = Cv.w + MN.w;
            mxv.x = Cv.x + MX.x; mxv.y = Cv.y + MX.y; mxv.z = Cv.z + MX.z; mxv.w = Cv.w + MX.w;
        } else {
            mnv = (f4){0.f, 0.f, 0.f, 0.f}; mxv = mnv;
        }
        ((f4*)&sAgg[nsub][0][0])[lane] = mean;
        ((f4*)&sAgg[nsub][1][0])[lane] = mnv;
        ((f4*)&sAgg[nsub][2][0])[lane] = mxv;
        ((f4*)&sAgg[nsub][3][0])[lane] = stdv;
    }
    if (lane < F) sX[nsub][lane] = xin[(size_t)i * F + lane];
    if (lane == 0) {
        float amp = logf(fmaxf((float)d, 1.f) + 1.f) / scal[0];
        samp[nsub][0] = amp; samp[nsub][1] = 1.f / amp;
    }
    __syncthreads();

    // ---- post-GEMM: coalesced Wt reads, LDS-broadcast features, 3 accumulators ----
    int kk = (lane < HID) ? lane : (HID - 1);
    int tw = kk / FO;
    const float* __restrict__ xb = sX[nsub];
    float y0 = 0.f, y1 = 0.f, y2 = 0.f;
#pragma unroll 2
    for (int f = 0; f < F; ++f) y0 += Wt[f * 64 + kk] * xb[f];
#pragma unroll
    for (int s = 0; s < 4; ++s) {
        const float* __restrict__ A = &sAgg[nsub][s][tw * F];
        const float* __restrict__ W1p = Wt + (size_t)(1 + s) * F * 64 + kk;
        const float* __restrict__ W2p = Wt + (size_t)(5 + s) * F * 64 + kk;
        const float* __restrict__ W3p = Wt + (size_t)(9 + s) * F * 64 + kk;
#pragma unroll 2
        for (int f = 0; f < F; ++f) {
            float av = A[f];
            y0 += W1p[f * 64] * av;
            y1 += W2p[f * 64] * av;
            y2 += W3p[f * 64] * av;
        }
    }
    float y = postb[kk] + y0 + samp[nsub][0] * y1 + samp[nsub][1] * y2;
    if (lane < HID) sY[nsub][lane] = y;
    __syncthreads();

    float o = linb[kk];
#pragma unroll 2
    for (int j2 = 0; j2 < HID; ++j2) o += Lt[j2 * 64 + kk] * sY[nsub][j2];
    if (lane < HID) hout[(size_t)i * HID + lane] = o;
}

// ---------- BN: one-pass partial sums + apply ----------
__global__ void k_bn_part(const float* __restrict__ h, float* __restrict__ acc) {
    __shared__ float ss[4][64], ss2[4][64];
    int t = threadIdx.x;
    int rs = t >> 6, c = t & 63;
    float s = 0.f, s2 = 0.f;
    if (c < HID) {
        int r0 = blockIdx.x * 200 + rs;
        int rend = blockIdx.x * 200 + 200;
        if (rend > NN) rend = NN;
        for (int r = r0; r < rend; r += 4) {
            float v = h[(size_t)r * HID + c];
            s += v; s2 += v * v;
        }
    }
    ss[rs][c] = s; ss2[rs][c] = s2;
    __syncthreads();
    if (t < HID) {
        float S = ss[0][t] + ss[1][t] + ss[2][t] + ss[3][t];
        float S2 = ss2[0][t] + ss2[1][t] + ss2[2][t] + ss2[3][t];
        atomicAdd(&acc[t], S);
        atomicAdd(&acc[64 + t], S2);
    }
}

__global__ void k_bn_relu(const float* __restrict__ hin, const float* __restrict__ acc,
                          const float* __restrict__ gamma, const float* __restrict__ beta,
                          float* __restrict__ hout) {
    int idx = blockIdx.x * 256 + threadIdx.x;
    if (idx < NN * HID) {
        int c = idx % HID;
        float mu = acc[c] * (1.f / NN);
        float var = acc[64 + c] * (1.f / NN) - mu * mu;
        float v = hin[idx];
        hout[idx] = fmaxf(gamma[c] * (v - mu) * rsqrtf(var + 1e-5f) + beta[c], 0.f);
    }
}

// ---------- pooling + head ----------
__global__ void k_gbounds(const int* __restrict__ batch, int* __restrict__ gstart) {
    int g = threadIdx.x;
    if (g <= NGROUPS) {
        int lo = 0, hi = NN;
        while (lo < hi) {
            int mid = (lo + hi) >> 1;
            if (batch[mid] < g) lo = mid + 1; else hi = mid;
        }
        gstart[g] = lo;
    }
}

__global__ void k_pool(const float* __restrict__ h, const int* __restrict__ gstart,
                       float* __restrict__ pooled) {
    int g = blockIdx.x, c = threadIdx.x;
    int beg = gstart[g], end = gstart[g + 1];
    if (c < HID) {
        float s = 0.f;
        for (int n = beg; n < end; ++n) s += h[(size_t)n * HID + c];
        pooled[g * HID + c] = s / fmaxf((float)(end - beg), 1.0f);
    }
}

__global__ void k_mlp(const float* __restrict__ pooled,
                      const float* __restrict__ W1, const float* __restrict__ b1,
                      const float* __restrict__ W2, const float* __restrict__ b2,
                      const float* __restrict__ W3, const float* __restrict__ b3,
                      float* __restrict__ out) {
    __shared__ float p[HID], h1[50], h2[25];
    int g = blockIdx.x, tid = threadIdx.x;
    if (tid < HID) p[tid] = pooled[g * HID + tid];
    __syncthreads();
    if (tid < 50) {
        float a = b1[tid];
        for (int k = 0; k < HID; ++k) a += W1[tid * HID + k] * p[k];
        h1[tid] = fmaxf(a, 0.f);
    }
    __syncthreads();
    if (tid < 25) {
        float a = b2[tid];
        for (int k = 0; k < 50; ++k) a += W2[tid * 50 + k] * h1[k];
        h2[tid] = fmaxf(a, 0.f);
    }
    __syncthreads();
    if (tid == 0) {
        float a = b3[0];
        for (int k = 0; k < 25; ++k) a += W3[k] * h2[k];
        out[g] = a;
    }
}

extern "C" void kernel_launch(void* const* d_in, const int* in_sizes, int n_in,
                              void* d_out, int out_size, void* d_ws, size_t ws_size,
                              hipStream_t stream) {
    const float* x      = (const float*)d_in[0];
    const int*   ei     = (const int*)d_in[1];
    const int*   batch  = (const int*)d_in[2];
    const float* preW0  = (const float*)d_in[3];
    const float* preb0  = (const float*)d_in[4];
    const float* postW0 = (const float*)d_in[5];
    const float* postb0 = (const float*)d_in[6];
    const float* linW0  = (const float*)d_in[7];
    const float* linb0  = (const float*)d_in[8];
    const float* gamma0 = (const float*)d_in[9];
    const float* beta0  = (const float*)d_in[10];
    const float* preW1  = (const float*)d_in[11];
    const float* preb1  = (const float*)d_in[12];
    const float* postW1 = (const float*)d_in[13];
    const float* postb1 = (const float*)d_in[14];
    const float* linW1  = (const float*)d_in[15];
    const float* linb1  = (const float*)d_in[16];
    const float* gamma1 = (const float*)d_in[17];
    const float* beta1  = (const float*)d_in[18];
    const float* mW1    = (const float*)d_in[19];
    const float* mb1    = (const float*)d_in[20];
    const float* mW2    = (const float*)d_in[21];
    const float* mb2    = (const float*)d_in[22];
    const float* mW3    = (const float*)d_in[23];
    const float* mb3    = (const float*)d_in[24];
    float* out = (float*)d_out;
    (void)in_sizes; (void)n_in; (void)out_size; (void)ws_size;

    char* ws = (char*)d_ws;
    size_t off = 0;
    auto alloc = [&](size_t bytes) -> void* {
        void* p = ws + off;
        off += (bytes + 255) & ~(size_t)255;
        return p;
    };
    int*   deg     = (int*)alloc((size_t)NN * 4);
    int*   offsets = (int*)alloc((size_t)(NN + 1) * 4);
    int*   cursor  = (int*)alloc((size_t)NN * 4);
    int*   csr_src = (int*)alloc((size_t)EE * 4);
    float* scal    = (float*)alloc(64);
    int*   gstart  = (int*)alloc((NGROUPS + 1) * 4);
    float* bnacc0  = (float*)alloc(128 * 4);
    float* bnacc1  = (float*)alloc(128 * 4);
    float* pooled  = (float*)alloc(NGROUPS * HID * 4);
    float* preWt0  = (float*)alloc((size_t)32 * 80 * 4);     // [2F0][TFP0]
    float* preWt1  = (float*)alloc((size_t)100 * 256 * 4);   // [2F1][TFP1]
    float* Wt0     = (float*)alloc((size_t)208 * 64 * 4);    // [13*F0][64]
    float* Wt1     = (float*)alloc((size_t)650 * 64 * 4);    // [13*F1][64]
    float* Lt0     = (float*)alloc((size_t)50 * 64 * 4);
    float* Lt1     = (float*)alloc((size_t)50 * 64 * 4);
    float* Cbuf    = (float*)alloc((size_t)NN * 256 * 4);
    float* Pbuf    = (float*)alloc((size_t)NN * 256 * 4);
    float* h1buf   = (float*)alloc((size_t)NN * HID * 4);
    float* h2buf   = (float*)alloc((size_t)NN * HID * 4);

    const int* src = ei;
    const int* dst = ei + EE;

    hipMemsetAsync(deg, 0, (size_t)NN * 4, stream);
    hipMemsetAsync(cursor, 0, (size_t)NN * 4, stream);
    hipMemsetAsync(bnacc0, 0, 128 * 4, stream);
    hipMemsetAsync(bnacc1, 0, 128 * 4, stream);

    // weight transposes (tiny, once per launch)
    k_transpose<<<(32 * 80 + 255) / 256, 256, 0, stream>>>(preW0, preWt0, 80, 32, 80);
    k_transpose<<<(100 * 256 + 255) / 256, 256, 0, stream>>>(preW1, preWt1, 250, 100, 256);
    k_transpose<<<(208 * 64 + 255) / 256, 256, 0, stream>>>(postW0, Wt0, 50, 208, 64);
    k_transpose<<<(650 * 64 + 255) / 256, 256, 0, stream>>>(postW1, Wt1, 50, 650, 64);
    k_transpose<<<(50 * 64 + 255) / 256, 256, 0, stream>>>(linW0, Lt0, 50, 50, 64);
    k_transpose<<<(50 * 64 + 255) / 256, 256, 0, stream>>>(linW1, Lt1, 50, 50, 64);

    k_deg<<<EE / 256, 256, 0, stream>>>(dst, deg);
    k_scan<<<1, 1024, 0, stream>>>(deg, offsets);
    k_avglog<<<1, 1024, 0, stream>>>(deg, scal);
    k_fill<<<EE / 256, 256, 0, stream>>>(src, dst, offsets, cursor, csr_src);

    // ---- conv0 (F=16, TF=80, TFP=80, EP=3) ----
    k_gemm_CP<INDIM, TW * INDIM, 80><<<NN / 16, 256, 0, stream>>>(x, preWt0, preb0, Cbuf, Pbuf);
    k_conv<INDIM, TW * INDIM, 80, 3><<<NN / 4, 256, 0, stream>>>(
        x, Cbuf, Pbuf, offsets, csr_src, scal, Wt0, postb0, Lt0, linb0, h1buf);
    k_bn_part<<<100, 256, 0, stream>>>(h1buf, bnacc0);
    k_bn_relu<<<(NN * HID + 255) / 256, 256, 0, stream>>>(h1buf, bnacc0, gamma0, beta0, h1buf);

    // ---- conv1 (F=50, TF=250, TFP=256, EP=1) ----
    k_gemm_CP<HID, TW * HID, 256><<<NN / 16, 256, 0, stream>>>(h1buf, preWt1, preb1, Cbuf, Pbuf);
    k_conv<HID, TW * HID, 256, 1><<<NN / 4, 256, 0, stream>>>(
        h1buf, Cbuf, Pbuf, offsets, csr_src, scal, Wt1, postb1, Lt1, linb1, h2buf);
    k_bn_part<<<100, 256, 0, stream>>>(h2buf, bnacc1);
    k_bn_relu<<<(NN * HID + 255) / 256, 256, 0, stream>>>(h2buf, bnacc1, gamma1, beta1, h2buf);

    // ---- pool + head ----
    k_gbounds<<<1, 128, 0, stream>>>(batch, gstart);
    k_pool<<<NGROUPS, 64, 0, stream>>>(h2buf, gstart, pooled);
    k_mlp<<<NGROUPS, 64, 0, stream>>>(pooled, mW1, mb1, mW2, mb2, mW3, mb3, out);
}

// Round 4
// 324.910 us; speedup vs baseline: 8.0292x; 1.4415x over previous
//
#include <hip/hip_runtime.h>
#include <math.h>
#include <float.h>

#define NN 20000
#define EE 320000
#define INDIM 16
#define HID 50
#define TW 5
#define FO 10
#define NGROUPS 64

typedef float f4 __attribute__((ext_vector_type(4)));
typedef float f2 __attribute__((ext_vector_type(2)));

__device__ inline f4 f4_min(f4 a, f4 b) {
    f4 r; r.x = fminf(a.x, b.x); r.y = fminf(a.y, b.y);
    r.z = fminf(a.z, b.z); r.w = fmaxf(-a.w, -b.w) * -1.0f;
    r.w = fminf(a.w, b.w); return r;
}
__device__ inline f4 f4_max(f4 a, f4 b) {
    f4 r; r.x = fmaxf(a.x, b.x); r.y = fmaxf(a.y, b.y);
    r.z = fmaxf(a.z, b.z); r.w = fmaxf(a.w, b.w); return r;
}
__device__ inline float sh3sum(float v, int g0, int G_) {
    return v + __shfl(v, g0 + G_, 64) + __shfl(v, g0 + 2 * G_, 64);
}
__device__ inline float sh3min(float v, int g0, int G_) {
    return fminf(fminf(v, __shfl(v, g0 + G_, 64)), __shfl(v, g0 + 2 * G_, 64));
}
__device__ inline float sh3max(float v, int g0, int G_) {
    return fmaxf(fmaxf(v, __shfl(v, g0 + G_, 64)), __shfl(v, g0 + 2 * G_, 64));
}
__device__ inline void acc4(float& acc, f4 w, float a0, float a1, float a2, float a3) {
    acc += w.x * a0; acc += w.y * a1; acc += w.z * a2; acc += w.w * a3;
}

// ---------- CSR build ----------
__global__ void k_deg(const int* __restrict__ dst, int* __restrict__ deg) {
    int e = blockIdx.x * 256 + threadIdx.x;
    if (e < EE) atomicAdd(&deg[dst[e]], 1);
}

__global__ void k_scan(const int* __restrict__ deg, int* __restrict__ offsets,
                       float* __restrict__ scal) {
    __shared__ int part[1024];
    __shared__ float fred[1024];
    const int CH = 20;
    int tid = threadIdx.x;
    int base = tid * CH;
    int loc[CH];
    int s = 0; float fs = 0.f;
    for (int c = 0; c < CH; ++c) {
        int idx = base + c;
        int v = (idx < NN) ? deg[idx] : 0;
        loc[c] = s; s += v;
        if (idx < NN) fs += logf((float)v + 1.0f);
    }
    part[tid] = s; fred[tid] = fs; __syncthreads();
    for (int off = 1; off < 1024; off <<= 1) {
        int v = (tid >= off) ? part[tid - off] : 0;
        __syncthreads();
        part[tid] += v;
        __syncthreads();
    }
    int pre = (tid > 0) ? part[tid - 1] : 0;
    for (int c = 0; c < CH; ++c) {
        int idx = base + c;
        if (idx < NN) offsets[idx] = pre + loc[c];
    }
    if (tid == 0) offsets[NN] = part[1023];
    for (int off = 512; off > 0; off >>= 1) {
        if (tid < off) fred[tid] += fred[tid + off];
        __syncthreads();
    }
    if (tid == 0) scal[0] = fred[0] / (float)NN;
}

__global__ void k_fill(const int* __restrict__ src, const int* __restrict__ dst,
                       const int* __restrict__ offsets, int* __restrict__ cursor,
                       int* __restrict__ csr_src) {
    int e = blockIdx.x * 256 + threadIdx.x;
    if (e < EE) {
        int d = dst[e];
        int pos = offsets[d] + atomicAdd(&cursor[d], 1);
        csr_src[pos] = src[e];
    }
}

// ---------- pack all weight layouts in one kernel ----------
__global__ void k_pack(const float* __restrict__ preW0, const float* __restrict__ preW1,
                       const float* __restrict__ postW0, const float* __restrict__ postW1,
                       const float* __restrict__ linW0, const float* __restrict__ linW1,
                       float* __restrict__ preWt0, float* __restrict__ preWt1,
                       float* __restrict__ Wx0, float* __restrict__ Wid0,
                       float* __restrict__ Wamp0, float* __restrict__ Watt0,
                       float* __restrict__ Wx1, float* __restrict__ Wid1,
                       float* __restrict__ Wamp1, float* __restrict__ Watt1,
                       float* __restrict__ Lt0, float* __restrict__ Lt1) {
    int idx = blockIdx.x * 256 + threadIdx.x;
    int job = blockIdx.y;
    int q = idx >> 8, k = (idx >> 2) & 63, j = idx & 3;
    switch (job) {
    case 0:  // preWt0 [32][80]
        if (idx < 32 * 80) { int c = idx / 80, r = idx % 80; preWt0[idx] = preW0[r * 32 + c]; }
        break;
    case 1:  // preWt1 [100][256], rows padded 250->256
        if (idx < 100 * 256) { int c = idx / 256, r = idx % 256; preWt1[idx] = (r < 250) ? preW1[r * 100 + c] : 0.f; }
        break;
    case 2:  // Wx0: 4 quads, F=16
        if (idx < 4 * 256) { int f = q * 4 + j; Wx0[idx] = (k < HID) ? postW0[k * 208 + f] : 0.f; }
        break;
    case 3:  // Wid0: 16 quads
        if (idx < 16 * 256) { int s = q / 4, f = (q % 4) * 4 + j; Wid0[idx] = (k < HID) ? postW0[k * 208 + (1 + s) * 16 + f] : 0.f; }
        break;
    case 4:
        if (idx < 16 * 256) { int s = q / 4, f = (q % 4) * 4 + j; Wamp0[idx] = (k < HID) ? postW0[k * 208 + (5 + s) * 16 + f] : 0.f; }
        break;
    case 5:
        if (idx < 16 * 256) { int s = q / 4, f = (q % 4) * 4 + j; Watt0[idx] = (k < HID) ? postW0[k * 208 + (9 + s) * 16 + f] : 0.f; }
        break;
    case 6:  // Wx1: 13 quads, F=50 (entries 50,51 zero)
        if (idx < 13 * 256) { int f = q * 4 + j; Wx1[idx] = (f < 50 && k < HID) ? postW1[k * 650 + f] : 0.f; }
        break;
    case 7:  // Wid1: 52 quads (4 segs x 13)
        if (idx < 52 * 256) { int s = q / 13, f = (q % 13) * 4 + j; Wid1[idx] = (f < 50 && k < HID) ? postW1[k * 650 + (1 + s) * 50 + f] : 0.f; }
        break;
    case 8:
        if (idx < 52 * 256) { int s = q / 13, f = (q % 13) * 4 + j; Wamp1[idx] = (f < 50 && k < HID) ? postW1[k * 650 + (5 + s) * 50 + f] : 0.f; }
        break;
    case 9:
        if (idx < 52 * 256) { int s = q / 13, f = (q % 13) * 4 + j; Watt1[idx] = (f < 50 && k < HID) ? postW1[k * 650 + (9 + s) * 50 + f] : 0.f; }
        break;
    case 10:  // Lt0: 13 quads
        if (idx < 13 * 256) { int f = q * 4 + j; Lt0[idx] = (f < 50 && k < HID) ? linW0[k * 50 + f] : 0.f; }
        break;
    case 11:
        if (idx < 13 * 256) { int f = q * 4 + j; Lt1[idx] = (f < 50 && k < HID) ? linW1[k * 50 + f] : 0.f; }
        break;
    }
}

// ---------- C = x@WL^T + b, P = x@WR^T with transposed weights preWt[2F][TFP] ----------
template <int F, int TF, int TFP>
__global__ __launch_bounds__(256, 4) void k_gemm_CP(
    const float* __restrict__ x, const float* __restrict__ preWt,
    const float* __restrict__ b,
    float* __restrict__ C, float* __restrict__ P) {
    const int NODES = 16;
    __shared__ float xs[NODES * F];
    int tid = threadIdx.x;
    int base = blockIdx.x * NODES;
    for (int idx = tid; idx < NODES * F; idx += 256) xs[idx] = x[(size_t)base * F + idx];
    __syncthreads();
    if (tid < TF) {
        float accC[NODES], accP[NODES];
#pragma unroll
        for (int n = 0; n < NODES; ++n) { accC[n] = 0.f; accP[n] = 0.f; }
        for (int f = 0; f < F; ++f) {
            float wl = preWt[f * TFP + tid];
            float wr = preWt[(F + f) * TFP + tid];
#pragma unroll
            for (int n = 0; n < NODES; ++n) {
                float xv = xs[n * F + f];
                accC[n] += xv * wl;
                accP[n] += xv * wr;
            }
        }
        float bb = b[tid];
        for (int n = 0; n < NODES; ++n) {
            C[((size_t)(base + n)) * TFP + tid] = accC[n] + bb;
            P[((size_t)(base + n)) * TFP + tid] = accP[n];
        }
    } else if (tid < TFP) {
        for (int n = 0; n < NODES; ++n) {
            C[((size_t)(base + n)) * TFP + tid] = 0.f;
            P[((size_t)(base + n)) * TFP + tid] = 0.f;
        }
    }
}

// ---------- fused gather-stats + post-GEMM + lin ----------
// 8 nodes/block, 4 waves; each wave gathers & posts 2 nodes (register-blocked).
// Weights packed [quad][64][4] -> one b128 coalesced load per lane per 4 features.
template <int F, int TFP, int EP, int SEGP>
__global__ __launch_bounds__(256, 3) void k_conv(
    const float* __restrict__ xin, const float* __restrict__ C, const float* __restrict__ P,
    const int* __restrict__ offsets, const int* __restrict__ csr,
    const float* __restrict__ scal,
    const float* __restrict__ Wx, const float* __restrict__ Wid,
    const float* __restrict__ Wamp, const float* __restrict__ Watt,
    const float* __restrict__ postb,
    const float* __restrict__ Lt, const float* __restrict__ linb,
    float* __restrict__ hout) {
    const int NB = 8;
    const int G = TFP / 4;
    const int SQ = SEGP / 4;
    __shared__ __align__(16) float sAgg[NB][5][TFP];
    __shared__ __align__(16) float sY[NB][56];
    __shared__ float samp[NB][2];
    int t = threadIdx.x;
    int w = t >> 6, lane = t & 63;
    int ibase = blockIdx.x * NB + 2 * w;

    for (int nn = 0; nn < 2; ++nn) {
        int nd = 2 * w + nn;
        int i = ibase + nn;
        int beg = offsets[i], end = offsets[i + 1];
        int d = end - beg;
        int g = (EP == 1) ? lane : (lane % G);
        int e = (EP == 1) ? 0 : (lane / G);
        bool act = (EP == 1) ? (g < G) : (e < EP);
        f4 S = {0.f, 0.f, 0.f, 0.f}, S2 = {0.f, 0.f, 0.f, 0.f};
        f4 MN = {FLT_MAX, FLT_MAX, FLT_MAX, FLT_MAX};
        f4 MX = {-FLT_MAX, -FLT_MAX, -FLT_MAX, -FLT_MAX};
        const f4* __restrict__ Pv = (const f4*)P;
        if (act) {
            if (EP == 1) {
                int j = beg;
                for (; j + 4 <= end; j += 4) {
                    int s0 = csr[j], s1 = csr[j + 1], s2 = csr[j + 2], s3 = csr[j + 3];
                    f4 a = Pv[(size_t)s0 * G + g];
                    f4 b = Pv[(size_t)s1 * G + g];
                    f4 c = Pv[(size_t)s2 * G + g];
                    f4 dd = Pv[(size_t)s3 * G + g];
                    S += a; S2 += a * a; MN = f4_min(MN, a); MX = f4_max(MX, a);
                    S += b; S2 += b * b; MN = f4_min(MN, b); MX = f4_max(MX, b);
                    S += c; S2 += c * c; MN = f4_min(MN, c); MX = f4_max(MX, c);
                    S += dd; S2 += dd * dd; MN = f4_min(MN, dd); MX = f4_max(MX, dd);
                }
                for (; j < end; ++j) {
                    int s0 = csr[j];
                    f4 a = Pv[(size_t)s0 * G + g];
                    S += a; S2 += a * a; MN = f4_min(MN, a); MX = f4_max(MX, a);
                }
            } else {
                int j = beg + e;
                for (; j + EP < end; j += 2 * EP) {
                    int s0 = csr[j], s1 = csr[j + EP];
                    f4 a = Pv[(size_t)s0 * G + g];
                    f4 b = Pv[(size_t)s1 * G + g];
                    S += a; S2 += a * a; MN = f4_min(MN, a); MX = f4_max(MX, a);
                    S += b; S2 += b * b; MN = f4_min(MN, b); MX = f4_max(MX, b);
                }
                if (j < end) {
                    int s0 = csr[j];
                    f4 a = Pv[(size_t)s0 * G + g];
                    S += a; S2 += a * a; MN = f4_min(MN, a); MX = f4_max(MX, a);
                }
            }
        }
        if (EP == 3) {
            int g0 = lane % G;
            S.x = sh3sum(S.x, g0, G); S.y = sh3sum(S.y, g0, G);
            S.z = sh3sum(S.z, g0, G); S.w = sh3sum(S.w, g0, G);
            S2.x = sh3sum(S2.x, g0, G); S2.y = sh3sum(S2.y, g0, G);
            S2.z = sh3sum(S2.z, g0, G); S2.w = sh3sum(S2.w, g0, G);
            MN.x = sh3min(MN.x, g0, G); MN.y = sh3min(MN.y, g0, G);
            MN.z = sh3min(MN.z, g0, G); MN.w = sh3min(MN.w, g0, G);
            MX.x = sh3max(MX.x, g0, G); MX.y = sh3max(MX.y, g0, G);
            MX.z = sh3max(MX.z, g0, G); MX.w = sh3max(MX.w, g0, G);
        }
        if (lane < G) {
            f4 Cv = ((const f4*)C)[(size_t)i * G + lane];
            float degf = (float)d;
            float rdegc = 1.0f / fmaxf(degf, 1.0f);
            f4 mean, sq, var, stdv, mnv, mxv;
            mean.x = (degf * Cv.x + S.x) * rdegc; mean.y = (degf * Cv.y + S.y) * rdegc;
            mean.z = (degf * Cv.z + S.z) * rdegc; mean.w = (degf * Cv.w + S.w) * rdegc;
            sq.x = degf * Cv.x * Cv.x + 2.f * Cv.x * S.x + S2.x;
            sq.y = degf * Cv.y * Cv.y + 2.f * Cv.y * S.y + S2.y;
            sq.z = degf * Cv.z * Cv.z + 2.f * Cv.z * S.z + S2.z;
            sq.w = degf * Cv.w * Cv.w + 2.f * Cv.w * S.w + S2.w;
            var.x = sq.x * rdegc - mean.x * mean.x; var.y = sq.y * rdegc - mean.y * mean.y;
            var.z = sq.z * rdegc - mean.z * mean.z; var.w = sq.w * rdegc - mean.w * mean.w;
            stdv.x = sqrtf(fmaxf(var.x, 0.f) + 1e-5f); stdv.y = sqrtf(fmaxf(var.y, 0.f) + 1e-5f);
            stdv.z = sqrtf(fmaxf(var.z, 0.f) + 1e-5f); stdv.w = sqrtf(fmaxf(var.w, 0.f) + 1e-5f);
            if (d > 0) {
                mnv.x = Cv.x + MN.x; mnv.y = Cv.y + MN.y; mnv.z = Cv.z + MN.z; mnv.w = Cv.w + MN.w;
                mxv.x = Cv.x + MX.x; mxv.y = Cv.y + MX.y; mxv.z = Cv.z + MX.z; mxv.w = Cv.w + MX.w;
            } else {
                mnv = (f4){0.f, 0.f, 0.f, 0.f}; mxv = mnv;
            }
            ((f4*)&sAgg[nd][0][0])[lane] = mean;
            ((f4*)&sAgg[nd][1][0])[lane] = mnv;
            ((f4*)&sAgg[nd][2][0])[lane] = mxv;
            ((f4*)&sAgg[nd][3][0])[lane] = stdv;
        }
        if (lane < F) sAgg[nd][4][lane] = xin[(size_t)i * F + lane];
        else if (lane < SEGP) sAgg[nd][4][lane] = 0.f;
        if (lane == 0) {
            float amp = logf(fmaxf((float)d, 1.f) + 1.f) / scal[0];
            samp[nd][0] = amp; samp[nd][1] = 1.f / amp;
        }
    }
    __syncthreads();  // lockstep waves for L1 weight-reuse

    int nd0 = 2 * w, nd1 = 2 * w + 1;
    int i0 = ibase, i1 = ibase + 1;
    int k = lane;
    int kk = (k < HID) ? k : (HID - 1);
    int tw = kk / FO;
    const f4* __restrict__ Wxv = (const f4*)Wx;
    const f4* __restrict__ Wiv = (const f4*)Wid;
    const f4* __restrict__ Wav = (const f4*)Wamp;
    const f4* __restrict__ Wtv = (const f4*)Watt;
    float y0a = 0.f, y1a = 0.f, y2a = 0.f, y0b = 0.f, y1b = 0.f, y2b = 0.f;

    // x segment
    const float* __restrict__ A0x = &sAgg[nd0][4][0];
    const float* __restrict__ A1x = &sAgg[nd1][4][0];
#pragma unroll
    for (int q = 0; q < SQ; ++q) {
        f4 wv = Wxv[q * 64 + k];
        f4 a0 = *(const f4*)(A0x + q * 4);
        f4 a1 = *(const f4*)(A1x + q * 4);
        acc4(y0a, wv, a0.x, a0.y, a0.z, a0.w);
        acc4(y0b, wv, a1.x, a1.y, a1.z, a1.w);
    }
    // agg segments: identity/amp/atten share each A read
#pragma unroll
    for (int s = 0; s < 4; ++s) {
        const float* __restrict__ A0 = &sAgg[nd0][s][tw * F];
        const float* __restrict__ A1 = &sAgg[nd1][s][tw * F];
#pragma unroll 4
        for (int fq = 0; fq < SQ; ++fq) {
            int q = s * SQ + fq;
            f4 wi = Wiv[q * 64 + k];
            f4 wa = Wav[q * 64 + k];
            f4 wt = Wtv[q * 64 + k];
            float a00, a01, a02, a03, a10, a11, a12, a13;
            if constexpr (F % 4 == 0) {
                f4 v0 = *(const f4*)(A0 + fq * 4);
                f4 v1 = *(const f4*)(A1 + fq * 4);
                a00 = v0.x; a01 = v0.y; a02 = v0.z; a03 = v0.w;
                a10 = v1.x; a11 = v1.y; a12 = v1.z; a13 = v1.w;
            } else {
                f2 p0 = *(const f2*)(A0 + fq * 4);
                f2 p1 = *(const f2*)(A0 + fq * 4 + 2);
                f2 q0 = *(const f2*)(A1 + fq * 4);
                f2 q1 = *(const f2*)(A1 + fq * 4 + 2);
                a00 = p0.x; a01 = p0.y; a02 = p1.x; a03 = p1.y;
                a10 = q0.x; a11 = q0.y; a12 = q1.x; a13 = q1.y;
            }
            acc4(y0a, wi, a00, a01, a02, a03);
            acc4(y1a, wa, a00, a01, a02, a03);
            acc4(y2a, wt, a00, a01, a02, a03);
            acc4(y0b, wi, a10, a11, a12, a13);
            acc4(y1b, wa, a10, a11, a12, a13);
            acc4(y2b, wt, a10, a11, a12, a13);
        }
    }
    float ya = postb[kk] + y0a + samp[nd0][0] * y1a + samp[nd0][1] * y2a;
    float yb = postb[kk] + y0b + samp[nd1][0] * y1b + samp[nd1][1] * y2b;
    if (lane < 56) {
        sY[nd0][lane] = (lane < HID) ? ya : 0.f;
        sY[nd1][lane] = (lane < HID) ? yb : 0.f;
    }
    // no barrier needed: sY rows are wave-private

    const f4* __restrict__ Lv = (const f4*)Lt;
    float oa = linb[kk], ob = oa;
#pragma unroll
    for (int q = 0; q < 13; ++q) {
        f4 lv = Lv[q * 64 + k];
        f4 s0 = *(const f4*)(&sY[nd0][q * 4]);
        f4 s1 = *(const f4*)(&sY[nd1][q * 4]);
        acc4(oa, lv, s0.x, s0.y, s0.z, s0.w);
        acc4(ob, lv, s1.x, s1.y, s1.z, s1.w);
    }
    if (lane < HID) {
        hout[(size_t)i0 * HID + lane] = oa;
        hout[(size_t)i1 * HID + lane] = ob;
    }
}

// ---------- BN: one-pass partial sums + apply ----------
__global__ void k_bn_part(const float* __restrict__ h, float* __restrict__ acc) {
    __shared__ float ss[4][64], ss2[4][64];
    int t = threadIdx.x;
    int rs = t >> 6, c = t & 63;
    float s = 0.f, s2 = 0.f;
    if (c < HID) {
        int r0 = blockIdx.x * 200 + rs;
        int rend = blockIdx.x * 200 + 200;
        if (rend > NN) rend = NN;
        for (int r = r0; r < rend; r += 4) {
            float v = h[(size_t)r * HID + c];
            s += v; s2 += v * v;
        }
    }
    ss[rs][c] = s; ss2[rs][c] = s2;
    __syncthreads();
    if (t < HID) {
        float S = ss[0][t] + ss[1][t] + ss[2][t] + ss[3][t];
        float S2 = ss2[0][t] + ss2[1][t] + ss2[2][t] + ss2[3][t];
        atomicAdd(&acc[t], S);
        atomicAdd(&acc[64 + t], S2);
    }
}

__global__ void k_bn_relu(const float* __restrict__ hin, const float* __restrict__ acc,
                          const float* __restrict__ gamma, const float* __restrict__ beta,
                          float* __restrict__ hout) {
    int idx = blockIdx.x * 256 + threadIdx.x;
    if (idx < NN * HID) {
        int c = idx % HID;
        float mu = acc[c] * (1.f / NN);
        float var = acc[64 + c] * (1.f / NN) - mu * mu;
        float v = hin[idx];
        hout[idx] = fmaxf(gamma[c] * (v - mu) * rsqrtf(var + 1e-5f) + beta[c], 0.f);
    }
}

// ---------- fused bounds + pooling + head MLP ----------
__global__ void k_head(const float* __restrict__ h, const int* __restrict__ batch,
                       const float* __restrict__ W1, const float* __restrict__ b1,
                       const float* __restrict__ W2, const float* __restrict__ b2,
                       const float* __restrict__ W3, const float* __restrict__ b3,
                       float* __restrict__ out) {
    __shared__ float sp[HID], h1[50], h2[25];
    __shared__ int sbound[2];
    int g = blockIdx.x, tid = threadIdx.x;
    if (tid < 2) {
        int target = g + tid;
        int lo = 0, hi = NN;
        while (lo < hi) {
            int mid = (lo + hi) >> 1;
            if (batch[mid] < target) lo = mid + 1; else hi = mid;
        }
        sbound[tid] = lo;
    }
    __syncthreads();
    int beg = sbound[0], end = sbound[1];
    if (tid < HID) {
        float s0 = 0.f, s1 = 0.f, s2 = 0.f, s3 = 0.f;
        int n = beg;
        for (; n + 4 <= end; n += 4) {
            s0 += h[(size_t)n * HID + tid];
            s1 += h[(size_t)(n + 1) * HID + tid];
            s2 += h[(size_t)(n + 2) * HID + tid];
            s3 += h[(size_t)(n + 3) * HID + tid];
        }
        for (; n < end; ++n) s0 += h[(size_t)n * HID + tid];
        sp[tid] = (s0 + s1 + s2 + s3) / fmaxf((float)(end - beg), 1.0f);
    }
    __syncthreads();
    if (tid < 50) {
        float a = b1[tid];
        for (int k = 0; k < HID; ++k) a += W1[tid * HID + k] * sp[k];
        h1[tid] = fmaxf(a, 0.f);
    }
    __syncthreads();
    if (tid < 25) {
        float a = b2[tid];
        for (int k = 0; k < 50; ++k) a += W2[tid * 50 + k] * h1[k];
        h2[tid] = fmaxf(a, 0.f);
    }
    __syncthreads();
    if (tid == 0) {
        float a = b3[0];
        for (int k = 0; k < 25; ++k) a += W3[k] * h2[k];
        out[g] = a;
    }
}

extern "C" void kernel_launch(void* const* d_in, const int* in_sizes, int n_in,
                              void* d_out, int out_size, void* d_ws, size_t ws_size,
                              hipStream_t stream) {
    const float* x      = (const float*)d_in[0];
    const int*   ei     = (const int*)d_in[1];
    const int*   batch  = (const int*)d_in[2];
    const float* preW0  = (const float*)d_in[3];
    const float* preb0  = (const float*)d_in[4];
    const float* postW0 = (const float*)d_in[5];
    const float* postb0 = (const float*)d_in[6];
    const float* linW0  = (const float*)d_in[7];
    const float* linb0  = (const float*)d_in[8];
    const float* gamma0 = (const float*)d_in[9];
    const float* beta0  = (const float*)d_in[10];
    const float* preW1  = (const float*)d_in[11];
    const float* preb1  = (const float*)d_in[12];
    const float* postW1 = (const float*)d_in[13];
    const float* postb1 = (const float*)d_in[14];
    const float* linW1  = (const float*)d_in[15];
    const float* linb1  = (const float*)d_in[16];
    const float* gamma1 = (const float*)d_in[17];
    const float* beta1  = (const float*)d_in[18];
    const float* mW1    = (const float*)d_in[19];
    const float* mb1    = (const float*)d_in[20];
    const float* mW2    = (const float*)d_in[21];
    const float* mb2    = (const float*)d_in[22];
    const float* mW3    = (const float*)d_in[23];
    const float* mb3    = (const float*)d_in[24];
    float* out = (float*)d_out;
    (void)in_sizes; (void)n_in; (void)out_size; (void)ws_size;

    char* ws = (char*)d_ws;
    size_t off = 0;
    auto alloc = [&](size_t bytes) -> void* {
        void* p = ws + off;
        off += (bytes + 255) & ~(size_t)255;
        return p;
    };
    int*   deg     = (int*)alloc((size_t)NN * 4);
    int*   offsets = (int*)alloc((size_t)(NN + 1) * 4);
    int*   cursor  = (int*)alloc((size_t)NN * 4);
    int*   csr_src = (int*)alloc((size_t)EE * 4);
    float* scal    = (float*)alloc(64);
    float* bnacc0  = (float*)alloc(128 * 4);
    float* bnacc1  = (float*)alloc(128 * 4);
    float* preWt0  = (float*)alloc((size_t)32 * 80 * 4);
    float* preWt1  = (float*)alloc((size_t)100 * 256 * 4);
    float* Wx0     = (float*)alloc((size_t)4 * 256 * 4);
    float* Wid0    = (float*)alloc((size_t)16 * 256 * 4);
    float* Wamp0   = (float*)alloc((size_t)16 * 256 * 4);
    float* Watt0   = (float*)alloc((size_t)16 * 256 * 4);
    float* Wx1     = (float*)alloc((size_t)13 * 256 * 4);
    float* Wid1    = (float*)alloc((size_t)52 * 256 * 4);
    float* Wamp1   = (float*)alloc((size_t)52 * 256 * 4);
    float* Watt1   = (float*)alloc((size_t)52 * 256 * 4);
    float* Lt0     = (float*)alloc((size_t)13 * 256 * 4);
    float* Lt1     = (float*)alloc((size_t)13 * 256 * 4);
    float* Cbuf    = (float*)alloc((size_t)NN * 256 * 4);
    float* Pbuf    = (float*)alloc((size_t)NN * 256 * 4);
    float* h1buf   = (float*)alloc((size_t)NN * HID * 4);
    float* h2buf   = (float*)alloc((size_t)NN * HID * 4);

    const int* src = ei;
    const int* dst = ei + EE;

    hipMemsetAsync(deg, 0, (size_t)NN * 4, stream);
    hipMemsetAsync(cursor, 0, (size_t)NN * 4, stream);
    hipMemsetAsync(bnacc0, 0, 128 * 4, stream);
    hipMemsetAsync(bnacc1, 0, 128 * 4, stream);

    k_pack<<<dim3(100, 12), 256, 0, stream>>>(preW0, preW1, postW0, postW1, linW0, linW1,
                                              preWt0, preWt1, Wx0, Wid0, Wamp0, Watt0,
                                              Wx1, Wid1, Wamp1, Watt1, Lt0, Lt1);
    k_deg<<<EE / 256, 256, 0, stream>>>(dst, deg);
    k_scan<<<1, 1024, 0, stream>>>(deg, offsets, scal);
    k_fill<<<EE / 256, 256, 0, stream>>>(src, dst, offsets, cursor, csr_src);

    // ---- conv0 (F=16, TF=80, TFP=80, EP=3, SEGP=16) ----
    k_gemm_CP<INDIM, 80, 80><<<NN / 16, 256, 0, stream>>>(x, preWt0, preb0, Cbuf, Pbuf);
    k_conv<INDIM, 80, 3, 16><<<NN / 8, 256, 0, stream>>>(
        x, Cbuf, Pbuf, offsets, csr_src, scal, Wx0, Wid0, Wamp0, Watt0, postb0, Lt0, linb0, h1buf);
    k_bn_part<<<100, 256, 0, stream>>>(h1buf, bnacc0);
    k_bn_relu<<<(NN * HID + 255) / 256, 256, 0, stream>>>(h1buf, bnacc0, gamma0, beta0, h1buf);

    // ---- conv1 (F=50, TF=250, TFP=256, EP=1, SEGP=52) ----
    k_gemm_CP<HID, 250, 256><<<NN / 16, 256, 0, stream>>>(h1buf, preWt1, preb1, Cbuf, Pbuf);
    k_conv<HID, 256, 1, 52><<<NN / 8, 256, 0, stream>>>(
        h1buf, Cbuf, Pbuf, offsets, csr_src, scal, Wx1, Wid1, Wamp1, Watt1, postb1, Lt1, linb1, h2buf);
    k_bn_part<<<100, 256, 0, stream>>>(h2buf, bnacc1);
    k_bn_relu<<<(NN * HID + 255) / 256, 256, 0, stream>>>(h2buf, bnacc1, gamma1, beta1, h2buf);

    // ---- pool + head ----
    k_head<<<NGROUPS, 64, 0, stream>>>(h2buf, batch, mW1, mb1, mW2, mb2, mW3, mb3, out);
}